// Round 1
// baseline (141.819 us; speedup 1.0000x reference)
//
#include <hip/hip_runtime.h>

// Problem constants (from reference setup_inputs)
constexpr int B = 128;
constexpr int A = 1024;
constexpr int M = 6;
constexpr int T = 16;

constexpr float AGENT_THRESH = 0.5f;
constexpr float X_DIS_THRESH = 1.5f;
constexpr float Y_DIS_THRESH = 3.0f;
constexpr float DIS_THRESH_SQ = 9.0f;   // dist > 3.0  <=>  dist^2 > 9.0 (dist >= 0)
constexpr float PEN = 100.0f;

// k1: 4 blocks per batch, 256 threads/block, 1 agent per thread.
// Writes per-block partial mins ws[blockIdx][32] where slot = t*2 + (0=x,1=y).
__global__ __launch_bounds__(256) void ppcl_k1(
    const float* __restrict__ ego,     // [B, T, 2]
    const float* __restrict__ fut,     // [B, A, M, T, 2]
    const float* __restrict__ score,   // [B, A, M]
    float* __restrict__ ws)            // [gridDim.x, 32]
{
    const int b     = blockIdx.x >> 2;
    const int agent = ((blockIdx.x & 3) << 8) + threadIdx.x;

    __shared__ float s_ego[T * 2];
    if (threadIdx.x < T * 2) s_ego[threadIdx.x] = ego[b * T * 2 + threadIdx.x];
    __syncthreads();

    // argmax over the 6 mode scores (first-max semantics via strict >)
    const float* sp = score + ((size_t)b * A + agent) * M;
    float best = sp[0];
    int   bm   = 0;
#pragma unroll
    for (int m = 1; m < M; ++m) {
        float s = sp[m];
        if (s > best) { best = s; bm = m; }
    }
    const bool lowconf = (best < AGENT_THRESH);

    // best-mode trajectory: 32 contiguous floats, 128B-aligned -> 8x float4
    const float4* tp = reinterpret_cast<const float4*>(
        fut + (((size_t)b * A + agent) * M + bm) * (T * 2));

    float xmin[T], ymin[T];
#pragma unroll
    for (int i = 0; i < 8; ++i) {
        float4 v = tp[i];
        {
            const int t = 2 * i;
            float dx = s_ego[2 * t]     - v.x;
            float dy = s_ego[2 * t + 1] - v.y;
            float d2 = dx * dx + dy * dy;
            float pen = (d2 > DIS_THRESH_SQ || lowconf) ? PEN : 0.0f;
            xmin[t] = fabsf(dx) + pen;
            ymin[t] = fabsf(dy) + pen;
        }
        {
            const int t = 2 * i + 1;
            float dx = s_ego[2 * t]     - v.z;
            float dy = s_ego[2 * t + 1] - v.w;
            float d2 = dx * dx + dy * dy;
            float pen = (d2 > DIS_THRESH_SQ || lowconf) ? PEN : 0.0f;
            xmin[t] = fabsf(dx) + pen;
            ymin[t] = fabsf(dy) + pen;
        }
    }

    // 64-lane butterfly min-reduce (wave = 64 on CDNA)
#pragma unroll
    for (int off = 32; off > 0; off >>= 1) {
#pragma unroll
        for (int t = 0; t < T; ++t) {
            xmin[t] = fminf(xmin[t], __shfl_xor(xmin[t], off, 64));
            ymin[t] = fminf(ymin[t], __shfl_xor(ymin[t], off, 64));
        }
    }

    __shared__ float s_red[4][T * 2];
    const int wave = threadIdx.x >> 6;
    const int lane = threadIdx.x & 63;
    if (lane == 0) {
#pragma unroll
        for (int t = 0; t < T; ++t) {
            s_red[wave][2 * t]     = xmin[t];
            s_red[wave][2 * t + 1] = ymin[t];
        }
    }
    __syncthreads();

    if (threadIdx.x < T * 2) {
        float m = fminf(fminf(s_red[0][threadIdx.x], s_red[1][threadIdx.x]),
                        fminf(s_red[2][threadIdx.x], s_red[3][threadIdx.x]));
        ws[(size_t)blockIdx.x * (T * 2) + threadIdx.x] = m;
    }
}

// k2: single 256-thread block. Final min over the 4 partial blocks per batch,
// hinge loss, mask, mean -> scalar.
__global__ __launch_bounds__(256) void ppcl_k2(
    const float* __restrict__ ws,     // [B*4, 32]
    const float* __restrict__ mask,   // [B, T]
    float* __restrict__ out)          // [1]
{
    float acc = 0.0f;
#pragma unroll
    for (int i = 0; i < 16; ++i) {
        const int v   = i * 256 + threadIdx.x;   // 0..4095 = (b, t, xy)
        const int b   = v >> 5;
        const int rem = v & 31;
        const int t   = rem >> 1;
        const int xy  = rem & 1;

        float m = ws[(size_t)(b * 4 + 0) * 32 + rem];
        m = fminf(m, ws[(size_t)(b * 4 + 1) * 32 + rem]);
        m = fminf(m, ws[(size_t)(b * 4 + 2) * 32 + rem]);
        m = fminf(m, ws[(size_t)(b * 4 + 3) * 32 + rem]);

        const float thr  = xy ? Y_DIS_THRESH : X_DIS_THRESH;
        float loss = (m <= thr) ? (thr - m) : 0.0f;
        loss *= mask[b * T + t];
        acc += loss;
    }

    // 64-lane sum reduce
#pragma unroll
    for (int off = 32; off > 0; off >>= 1) acc += __shfl_xor(acc, off, 64);

    __shared__ float s[4];
    const int wave = threadIdx.x >> 6;
    const int lane = threadIdx.x & 63;
    if (lane == 0) s[wave] = acc;
    __syncthreads();
    if (threadIdx.x == 0)
        out[0] = (s[0] + s[1] + s[2] + s[3]) * (1.0f / (B * T * 2));
}

extern "C" void kernel_launch(void* const* d_in, const int* in_sizes, int n_in,
                              void* d_out, int out_size, void* d_ws, size_t ws_size,
                              hipStream_t stream) {
    const float* ego   = (const float*)d_in[0];  // [B, T, 2]
    const float* fut   = (const float*)d_in[1];  // [B, A, M, T, 2]
    const float* score = (const float*)d_in[2];  // [B, A, M]
    const float* mask  = (const float*)d_in[3];  // [B, T]
    float* out = (float*)d_out;
    float* ws  = (float*)d_ws;                   // needs 512*32*4 = 64 KB

    ppcl_k1<<<B * 4, 256, 0, stream>>>(ego, fut, score, ws);
    ppcl_k2<<<1, 256, 0, stream>>>(ws, mask, out);
}